// Round 11
// baseline (288.567 us; speedup 1.0000x reference)
//
#include <hip/hip_runtime.h>
#include <math.h>

// ---------------------------------------------------------------------------
// R-GCN (basis decomposition, B=2), 2 layers.
//   C[n, 0:192] = x[n,:] @ [loop_w | basis0 | basis1]   (dense, MFMA bf16x3)
//   self = C[:,0:64]+bias ;  hb2[n][j] = (C[n,64+j], C[n,128+j])  (float2)
//   out[n] = act(self[n] + sum_{e: dst=n} c0*hb2[src][j].x + c1*hb2[src][j].y)
//
// Dense via matrix cores with fp32 emulation: x = xh + xl, w = wh + wl
// (bf16 hi/lo, RNE); C = xh*wh + xh*wl + xl*wh  (xl*wl ~ 2^-18, dropped).
//
// CSR build, atomic-light (r9 lesson: no hot-line global atomics; r10 refine:
// no global atomics at all in count, single-pass scatter):
//   1) bkt_count: plain per-(chunk,bucket) counts (no memset, no atomics)
//   2) bkt_scan:  in-place chunk-prefix per bucket + bucket exclusive scan
//   3) bkt_scatter: single pass, base = boff+prefix, LDS cursors
//   4) bkt_sort: per-bucket LDS counting sort -> node-grouped rec2 + rowptr
// Aggregation: one wave per node; HALF-WAVE float4 gathers (2 edges/wave,
// 512B per half-wave), 16-edge MLP, __shfl_xor(32) combine.
// ---------------------------------------------------------------------------

typedef short          short8 __attribute__((ext_vector_type(8)));
typedef float          f32x4  __attribute__((ext_vector_type(4)));
typedef unsigned short u16;

#define NCHUNK 256       // chunk blocks for count/scatter

static __device__ __forceinline__ u16 bf16_rne(float x) {
    unsigned u = __float_as_uint(x);
    return (u16)((u + 0x7fffu + ((u >> 16) & 1u)) >> 16);
}
static __device__ __forceinline__ float bf16_f32(u16 h) {
    return __uint_as_float(((unsigned)h) << 16);
}

// ---------------- W pre-convert: Wt[192][K] bf16 hi/lo (transposed) --------
__global__ __launch_bounds__(256) void wconv(
    const float* __restrict__ loopw1, const float* __restrict__ basis1,
    const float* __restrict__ loopw2, const float* __restrict__ basis2,
    u16* __restrict__ wt1h, u16* __restrict__ wt1l,
    u16* __restrict__ wt2h, u16* __restrict__ wt2l)
{
    const int tid = blockIdx.x * 256 + threadIdx.x;
    if (tid < 192 * 128) {                       // layer 1, K=128
        const int j = tid >> 7, k = tid & 127;
        const float w = (j < 64)
            ? loopw1[k * 64 + j]
            : basis1[(size_t)((j - 64) >> 6) * (128 * 64) + k * 64 + ((j - 64) & 63)];
        const u16 h = bf16_rne(w);
        wt1h[tid] = h;
        wt1l[tid] = bf16_rne(w - bf16_f32(h));
    }
    if (tid < 192 * 64) {                        // layer 2, K=64
        const int j = tid >> 6, k = tid & 63;
        const float w = (j < 64)
            ? loopw2[k * 64 + j]
            : basis2[(size_t)((j - 64) >> 6) * (64 * 64) + k * 64 + ((j - 64) & 63)];
        const u16 h = bf16_rne(w);
        wt2h[tid] = h;
        wt2l[tid] = bf16_rne(w - bf16_f32(h));
    }
}

// ---------------- dense: 128 nodes/block, 8 waves, W in LDS ----------------
template<int K>
__global__ __launch_bounds__(512, 2) void rgcn_dense_mfma(
    const float* __restrict__ x,     // [N][K] f32
    const u16* __restrict__ wth,     // [192][K] bf16 hi (transposed)
    const u16* __restrict__ wtl,     // [192][K] bf16 lo
    const float* __restrict__ bias,  // [64]
    float* __restrict__ self,        // [N][64]  = x@loopw + bias
    float2* __restrict__ hb2,        // [N][64]  = (x@basis0, x@basis1) pairs
    int nNodes)
{
    constexpr int KC  = K / 32;          // mfma K-steps
    constexpr int GW  = K / 8;           // 16B granules per (col,split)
    constexpr int GMW = GW - 1;          // granule XOR mask
    __shared__ u16 wlds[96 * 2 * K];     // one 96-col half of W (hi+lo)

    const int n0   = blockIdx.x * 128;
    const int lane = threadIdx.x & 63;
    const int w    = threadIdx.x >> 6;   // 0..7
    const int rl   = lane & 15;          // A row / B col / D col
    const int kb   = lane >> 4;          // k-block

    // ---- A fragments: global -> reg, convert to bf16 hi/lo ----
    const int row = n0 + w * 16 + rl;
    short8 Ah[KC], Al[KC];
    #pragma unroll
    for (int kc = 0; kc < KC; ++kc) {
        float v[8];
        if (row < nNodes) {
            const float* xp = x + (size_t)row * K + kc * 32 + kb * 8;
            const float4 a = *reinterpret_cast<const float4*>(xp);
            const float4 b = *reinterpret_cast<const float4*>(xp + 4);
            v[0] = a.x; v[1] = a.y; v[2] = a.z; v[3] = a.w;
            v[4] = b.x; v[5] = b.y; v[6] = b.z; v[7] = b.w;
        } else {
            #pragma unroll
            for (int i = 0; i < 8; ++i) v[i] = 0.f;
        }
        #pragma unroll
        for (int i = 0; i < 8; ++i) {
            const u16 h = bf16_rne(v[i]);
            Ah[kc][i] = (short)h;
            Al[kc][i] = (short)bf16_rne(v[i] - bf16_f32(h));
        }
    }

    f32x4 acc[12];
    #pragma unroll
    for (int j = 0; j < 12; ++j) acc[j] = (f32x4){0.f, 0.f, 0.f, 0.f};

    #pragma unroll
    for (int hf = 0; hf < 2; ++hf) {
        if (hf) __syncthreads();         // protect LDS before overwrite
        // ---- stage 96 cols of W (hi+lo) into LDS, XOR-swizzled ----
        for (int gi = threadIdx.x; gi < 96 * 2 * GW; gi += 512) {
            const int ch = gi / (2 * GW);
            const int r  = gi - ch * 2 * GW;
            const int s  = r / GW;
            const int g  = r - s * GW;
            const u16* sp = (s == 0 ? wth : wtl)
                          + (size_t)(hf * 96 + ch) * K + g * 8;
            const short8 vv = *reinterpret_cast<const short8*>(sp);
            *reinterpret_cast<short8*>(
                &wlds[((ch * 2 + s) * GW + (g ^ (ch & GMW))) * 8]) = vv;
        }
        __syncthreads();

        #pragma unroll
        for (int j16h = 0; j16h < 6; ++j16h) {
            const int ch = j16h * 16 + rl;
            const u16* bbase = &wlds[(ch * 2) * GW * 8];
            #pragma unroll
            for (int kc = 0; kc < KC; ++kc) {
                const int gp = (kc * 4 + kb) ^ (ch & GMW);
                const short8 Bh =
                    *reinterpret_cast<const short8*>(bbase + gp * 8);
                const short8 Bl =
                    *reinterpret_cast<const short8*>(bbase + (GW + gp) * 8);
                f32x4 a = acc[hf * 6 + j16h];
                a = __builtin_amdgcn_mfma_f32_16x16x32_bf16(Ah[kc], Bh, a, 0, 0, 0);
                a = __builtin_amdgcn_mfma_f32_16x16x32_bf16(Ah[kc], Bl, a, 0, 0, 0);
                a = __builtin_amdgcn_mfma_f32_16x16x32_bf16(Al[kc], Bh, a, 0, 0, 0);
                acc[hf * 6 + j16h] = a;
            }
        }
    }

    // ---- epilogue: D[(kb*4+r)][rl] ----
    const int rowbase = n0 + w * 16 + kb * 4;
    #pragma unroll
    for (int j16 = 0; j16 < 4; ++j16) {          // cols 0..63 -> self + bias
        const float bj = bias[j16 * 16 + rl];
        #pragma unroll
        for (int r = 0; r < 4; ++r) {
            const int rr = rowbase + r;
            if (rr < nNodes)
                self[(size_t)rr * 64 + j16 * 16 + rl] = acc[j16][r] + bj;
        }
    }
    #pragma unroll
    for (int j16 = 4; j16 < 8; ++j16) {          // (basis0, basis1) pairs
        #pragma unroll
        for (int r = 0; r < 4; ++r) {
            const int rr = rowbase + r;
            if (rr < nNodes)
                hb2[(size_t)rr * 64 + (j16 - 4) * 16 + rl] =
                    make_float2(acc[j16][r], acc[j16 + 4][r]);
        }
    }
}

// ---------------- bucket build: no global atomics ------------------------
// block c owns edges [c*chunk, min(E,(c+1)*chunk))
__global__ __launch_bounds__(256) void bkt_count(
    const int* __restrict__ dst, int* __restrict__ cnt, int nE, int nB)
{
    __shared__ int lh[1024];
    const int t = threadIdx.x;
    for (int b = t; b < 1024; b += 256) lh[b] = 0;
    __syncthreads();
    const int chunk = (nE + NCHUNK - 1) / NCHUNK;
    const int e0 = blockIdx.x * chunk;
    const int e1 = min(nE, e0 + chunk);
    for (int e = e0 + t; e < e1; e += 256)
        atomicAdd(&lh[dst[e] >> 7], 1);
    __syncthreads();
    for (int b = t; b < nB; b += 256)
        cnt[blockIdx.x * nB + b] = lh[b];       // plain store
}

// cnt[p][b] -> in-place exclusive chunk-prefix (per bucket); boff = bucket scan
__global__ __launch_bounds__(1024) void bkt_scan(
    int* __restrict__ cnt, int* __restrict__ boff, int nB, int nE)
{
    __shared__ int sm[1024];
    const int t = threadIdx.x;
    int run = 0;
    if (t < nB) {
        for (int p = 0; p < NCHUNK; ++p) {      // coalesced at fixed p
            const int c = cnt[p * nB + t];
            cnt[p * nB + t] = run;
            run += c;
        }
    }
    sm[t] = (t < nB) ? run : 0;
    __syncthreads();
    for (int off = 1; off < 1024; off <<= 1) {  // Hillis-Steele inclusive
        const int u = (t >= off) ? sm[t - off] : 0;
        __syncthreads();
        sm[t] += u;
        __syncthreads();
    }
    if (t < nB) boff[t] = sm[t] - run;          // exclusive
    if (t == 0) boff[nB] = nE;
}

// rec = dl(7)<<23 | src(17)<<6 | et(6); single pass, LDS cursors
__global__ __launch_bounds__(256) void bkt_scatter(
    const int* __restrict__ src, const int* __restrict__ dst,
    const int* __restrict__ et, const int* __restrict__ cnt,
    const int* __restrict__ boff, unsigned* __restrict__ rec,
    int nE, int nB)
{
    __shared__ int lcur[1024];
    const int t = threadIdx.x;
    const int c = blockIdx.x;
    for (int b = t; b < nB; b += 256)
        lcur[b] = boff[b] + cnt[c * nB + b];
    __syncthreads();
    const int chunk = (nE + NCHUNK - 1) / NCHUNK;
    const int e0 = c * chunk;
    const int e1 = min(nE, e0 + chunk);
    for (int e = e0 + t; e < e1; e += 256) {
        const int d = dst[e];
        const int p = atomicAdd(&lcur[d >> 7], 1);
        rec[p] = ((unsigned)(d & 127) << 23)
               | ((unsigned)src[e] << 6)
               | (unsigned)et[e];
    }
}

// ---------------- per-bucket counting sort by node; emits rowptr -----------
__global__ __launch_bounds__(256) void bkt_sort(
    const unsigned* __restrict__ rec, unsigned* __restrict__ rec2,
    const int* __restrict__ boff, int* __restrict__ rowptr,
    int nNodes)
{
    __shared__ int cnt[128];
    __shared__ int pos[128];
    const int b = blockIdx.x;
    const int t = threadIdx.x;
    const int beg = boff[b], end = boff[b + 1];
    if (t < 128) cnt[t] = 0;
    __syncthreads();
    for (int i = beg + t; i < end; i += 256)
        atomicAdd(&cnt[rec[i] >> 23], 1);
    __syncthreads();
    if (t < 128) pos[t] = cnt[t];
    __syncthreads();
    for (int off = 1; off < 128; off <<= 1) {     // Hillis-Steele inclusive
        int u = 0;
        if (t < 128 && t >= off) u = pos[t - off];
        __syncthreads();
        if (t < 128) pos[t] += u;
        __syncthreads();
    }
    if (t < 128) {
        const int ex = beg + pos[t] - cnt[t];     // exclusive + bucket base
        pos[t] = ex;
        const int n = (b << 7) + t;
        if (n < nNodes) rowptr[n] = ex;
    }
    __syncthreads();
    for (int i = beg + t; i < end; i += 256) {
        const unsigned r = rec[i];
        const int p = atomicAdd(&pos[r >> 23], 1);
        rec2[p] = r;                               // bucket-window write
    }
}

// ---------------- edge aggregation: one wave per node, half-wave gathers ---
template<int ACT>   // 0 = tanh, 1 = relu
__global__ __launch_bounds__(256) void rgcn_agg(
    const float4* __restrict__ hb4,     // [N][32] float4 (=[N][64] float2)
    const float* __restrict__ comp,     // [R][2]
    const int* __restrict__ rowptr,     // [N], node-sorted rec2 offsets
    const unsigned* __restrict__ rec2,  // [E] node-grouped
    float* __restrict__ io,             // in: self+bias, out: act(self+agg)
    int nNodes, int nEdges)
{
    const int lane = threadIdx.x & 63;
    const int hl   = lane >> 5;         // 0: even edge of pair, 1: odd
    const int q    = lane & 31;         // float4 index (cols 2q, 2q+1)
    const int w  = (blockIdx.x * 256 + threadIdx.x) >> 6;
    const int nW = (gridDim.x * 256) >> 6;
    const float2* __restrict__ comp2 = reinterpret_cast<const float2*>(comp);
    for (int n = w; n < nNodes; n += nW) {
        const int beg = rowptr[n];
        const int end = (n == nNodes - 1) ? nEdges : rowptr[n + 1];
        const float2 self =
            *reinterpret_cast<const float2*>(io + (size_t)n * 64 + 2 * q);
        float accA = 0.f, accB = 0.f;
        for (int base = beg; base < end; base += 64) {
            const int cnt = min(64, end - base);
            const unsigned r = (lane < cnt) ? rec2[base + lane] : 0u;
            int i = 0;
            for (; i + 16 <= cnt; i += 16) {      // 8 pairs, 8 dwordx4/lane
                unsigned rr[8]; float4 v[8];
                #pragma unroll
                for (int k = 0; k < 8; ++k) {
                    rr[k] = __shfl(r, i + 2 * k + hl);
                    v[k] = hb4[(size_t)((rr[k] >> 6) & 0x1FFFFu) * 32 + q];
                }
                #pragma unroll
                for (int k = 0; k < 8; ++k) {
                    const float2 c = comp2[rr[k] & 63u];
                    accA = fmaf(c.x, v[k].x, accA);
                    accA = fmaf(c.y, v[k].y, accA);
                    accB = fmaf(c.x, v[k].z, accB);
                    accB = fmaf(c.y, v[k].w, accB);
                }
            }
            for (; i + 2 <= cnt; i += 2) {        // leftover pairs
                const unsigned rk = __shfl(r, i + hl);
                const float4 v = hb4[(size_t)((rk >> 6) & 0x1FFFFu) * 32 + q];
                const float2 c = comp2[rk & 63u];
                accA = fmaf(c.x, v.x, accA); accA = fmaf(c.y, v.y, accA);
                accB = fmaf(c.x, v.z, accB); accB = fmaf(c.y, v.w, accB);
            }
            if (i < cnt) {                        // single tail edge
                const unsigned rk = __shfl(r, i);
                const float4 v = hb4[(size_t)((rk >> 6) & 0x1FFFFu) * 32 + q];
                float2 c = comp2[rk & 63u];
                if (hl) { c.x = 0.f; c.y = 0.f; } // hi half contributes 0
                accA = fmaf(c.x, v.x, accA); accA = fmaf(c.y, v.y, accA);
                accB = fmaf(c.x, v.z, accB); accB = fmaf(c.y, v.w, accB);
            }
        }
        accA += __shfl_xor(accA, 32);             // combine halves
        accB += __shfl_xor(accB, 32);
        if (hl == 0) {
            float oA = self.x + accA, oB = self.y + accB;
            if (ACT == 0) { oA = tanhf(oA); oB = tanhf(oB); }
            else          { oA = fmaxf(oA, 0.f); oB = fmaxf(oB, 0.f); }
            *reinterpret_cast<float2*>(io + (size_t)n * 64 + 2 * q) =
                make_float2(oA, oB);
        }
    }
}

// ---------------------------------------------------------------------------
extern "C" void kernel_launch(void* const* d_in, const int* in_sizes, int n_in,
                              void* d_out, int out_size, void* d_ws, size_t ws_size,
                              hipStream_t stream)
{
    const float* node_emb = (const float*)d_in[0];   // [N][128]
    const float* basis1   = (const float*)d_in[1];   // [2][128][64]
    const float* comp1    = (const float*)d_in[2];   // [R][2]
    const float* loop_w1  = (const float*)d_in[3];   // [128][64]
    const float* bias1    = (const float*)d_in[4];   // [64]
    const float* basis2   = (const float*)d_in[5];   // [2][64][64]
    const float* comp2    = (const float*)d_in[6];   // [R][2]
    const float* loop_w2  = (const float*)d_in[7];   // [64][64]
    const float* bias2    = (const float*)d_in[8];   // [64]
    const int*   src      = (const int*)d_in[9];     // [E]
    const int*   dst      = (const int*)d_in[10];    // [E]
    const int*   et       = (const int*)d_in[11];    // [E]

    const int N = in_sizes[0] / 128;
    const int E = in_sizes[9];
    const int nB = (N + 127) / 128;                  // dst buckets (<=1024)

    float* out = (float*)d_out;                      // [N][64]

    // workspace layout
    float*    hb     = (float*)d_ws;                 // N*128 f (float4 [N][32])
    float*    h      = hb + (size_t)N * 128;         // N*64 f
    unsigned* rec    = (unsigned*)(h + (size_t)N * 64); // E u32 (bucket-grouped)
    unsigned* rec2   = rec + E;                      // E u32 (node-grouped)
    int*      cnt    = (int*)(rec2 + E);             // NCHUNK*nB
    int*      boff   = cnt + NCHUNK * nB;            // nB+1
    int*      rowptr = boff + nB + 1;                // N
    u16*      wt1h   = (u16*)(rowptr + N);           // 192*128
    u16*      wt1l   = wt1h + 192 * 128;
    u16*      wt2h   = wt1l + 192 * 128;             // 192*64
    u16*      wt2l   = wt2h + 192 * 64;

    const int nBlkDense = (N + 127) / 128;
    const int nBlkAgg   = (N + 3) / 4;               // 1 wave per node

    // ---- W pre-convert (bf16 hi/lo, transposed) ----
    wconv<<<96, 256, 0, stream>>>(loop_w1, basis1, loop_w2, basis2,
                                  wt1h, wt1l, wt2h, wt2l);

    // ---- per-node CSR: count -> scan -> single-pass scatter -> sort ----
    bkt_count  <<<NCHUNK, 256, 0, stream>>>(dst, cnt, E, nB);
    bkt_scan   <<<1,     1024, 0, stream>>>(cnt, boff, nB, E);
    bkt_scatter<<<NCHUNK, 256, 0, stream>>>(src, dst, et, cnt, boff, rec, E, nB);
    bkt_sort   <<<nB,     256, 0, stream>>>(rec, rec2, boff, rowptr, N);

    // ---- layer 1 ----
    rgcn_dense_mfma<128><<<nBlkDense, 512, 0, stream>>>(
        node_emb, wt1h, wt1l, bias1, h, (float2*)hb, N);
    rgcn_agg<0><<<nBlkAgg, 256, 0, stream>>>(
        (const float4*)hb, comp1, rowptr, rec2, h, N, E);

    // ---- layer 2 ----
    rgcn_dense_mfma<64><<<nBlkDense, 512, 0, stream>>>(
        h, wt2h, wt2l, bias2, out, (float2*)hb, N);
    rgcn_agg<1><<<nBlkAgg, 256, 0, stream>>>(
        (const float4*)hb, comp2, rowptr, rec2, out, N, E);
}

// Round 12
// 273.521 us; speedup vs baseline: 1.0550x; 1.0550x over previous
//
#include <hip/hip_runtime.h>
#include <math.h>

// ---------------------------------------------------------------------------
// R-GCN (basis decomposition, B=2), 2 layers.
//   C[n, 0:192] = x[n,:] @ [loop_w | basis0 | basis1]   (dense, MFMA bf16x3)
//   self = C[:,0:64]+bias ;  hb2[n][j] = (C[n,64+j], C[n,128+j])  (float2)
//   out[n] = act(self[n] + sum_{e: dst=n} c0*hb2[src][j].x + c1*hb2[src][j].y)
//
// Dense via matrix cores with fp32 emulation: x = xh + xl, w = wh + wl
// (bf16 hi/lo, RNE); C = xh*wh + xh*wl + xl*wh  (xl*wl ~ 2^-18, dropped).
//
// CSR build, fully parallel (r9: no hot-line atomics; r12: no single-block
// serial scan):
//   1) bkt_count:    per-(chunk,bucket) counts, plain stores
//   2) bkt_chunkscan: one block per bucket, 256-wide scan of chunk counts
//   3) bkt_boff:     single small block scans 782 bucket totals
//   4) bkt_scatter:  single pass, base = boff + chunk prefix, LDS cursors
//   5) bkt_sort:     per-bucket LDS counting sort -> rec2 + per-node rowptr
// Aggregation: one wave per node, half-wave float4 gathers; ALWAYS 8 loads
// in flight (indices clamped, coeffs zeroed past cnt) -> MLP independent of
// node degree (r11 lesson: deg~10 nodes were 5 serial gather rounds).
// ---------------------------------------------------------------------------

typedef short          short8 __attribute__((ext_vector_type(8)));
typedef float          f32x4  __attribute__((ext_vector_type(4)));
typedef unsigned short u16;

#define NCHUNK 256       // chunk blocks for count/scatter

static __device__ __forceinline__ u16 bf16_rne(float x) {
    unsigned u = __float_as_uint(x);
    return (u16)((u + 0x7fffu + ((u >> 16) & 1u)) >> 16);
}
static __device__ __forceinline__ float bf16_f32(u16 h) {
    return __uint_as_float(((unsigned)h) << 16);
}

// ---------------- W pre-convert: Wt[192][K] bf16 hi/lo (transposed) --------
__global__ __launch_bounds__(256) void wconv(
    const float* __restrict__ loopw1, const float* __restrict__ basis1,
    const float* __restrict__ loopw2, const float* __restrict__ basis2,
    u16* __restrict__ wt1h, u16* __restrict__ wt1l,
    u16* __restrict__ wt2h, u16* __restrict__ wt2l)
{
    const int tid = blockIdx.x * 256 + threadIdx.x;
    if (tid < 192 * 128) {                       // layer 1, K=128
        const int j = tid >> 7, k = tid & 127;
        const float w = (j < 64)
            ? loopw1[k * 64 + j]
            : basis1[(size_t)((j - 64) >> 6) * (128 * 64) + k * 64 + ((j - 64) & 63)];
        const u16 h = bf16_rne(w);
        wt1h[tid] = h;
        wt1l[tid] = bf16_rne(w - bf16_f32(h));
    }
    if (tid < 192 * 64) {                        // layer 2, K=64
        const int j = tid >> 6, k = tid & 63;
        const float w = (j < 64)
            ? loopw2[k * 64 + j]
            : basis2[(size_t)((j - 64) >> 6) * (64 * 64) + k * 64 + ((j - 64) & 63)];
        const u16 h = bf16_rne(w);
        wt2h[tid] = h;
        wt2l[tid] = bf16_rne(w - bf16_f32(h));
    }
}

// ---------------- dense: 128 nodes/block, 8 waves, W in LDS ----------------
template<int K>
__global__ __launch_bounds__(512, 2) void rgcn_dense_mfma(
    const float* __restrict__ x,     // [N][K] f32
    const u16* __restrict__ wth,     // [192][K] bf16 hi (transposed)
    const u16* __restrict__ wtl,     // [192][K] bf16 lo
    const float* __restrict__ bias,  // [64]
    float* __restrict__ self,        // [N][64]  = x@loopw + bias
    float2* __restrict__ hb2,        // [N][64]  = (x@basis0, x@basis1) pairs
    int nNodes)
{
    constexpr int KC  = K / 32;          // mfma K-steps
    constexpr int GW  = K / 8;           // 16B granules per (col,split)
    constexpr int GMW = GW - 1;          // granule XOR mask
    __shared__ u16 wlds[96 * 2 * K];     // one 96-col half of W (hi+lo)

    const int n0   = blockIdx.x * 128;
    const int lane = threadIdx.x & 63;
    const int w    = threadIdx.x >> 6;   // 0..7
    const int rl   = lane & 15;          // A row / B col / D col
    const int kb   = lane >> 4;          // k-block

    // ---- A fragments: global -> reg, convert to bf16 hi/lo ----
    const int row = n0 + w * 16 + rl;
    short8 Ah[KC], Al[KC];
    #pragma unroll
    for (int kc = 0; kc < KC; ++kc) {
        float v[8];
        if (row < nNodes) {
            const float* xp = x + (size_t)row * K + kc * 32 + kb * 8;
            const float4 a = *reinterpret_cast<const float4*>(xp);
            const float4 b = *reinterpret_cast<const float4*>(xp + 4);
            v[0] = a.x; v[1] = a.y; v[2] = a.z; v[3] = a.w;
            v[4] = b.x; v[5] = b.y; v[6] = b.z; v[7] = b.w;
        } else {
            #pragma unroll
            for (int i = 0; i < 8; ++i) v[i] = 0.f;
        }
        #pragma unroll
        for (int i = 0; i < 8; ++i) {
            const u16 h = bf16_rne(v[i]);
            Ah[kc][i] = (short)h;
            Al[kc][i] = (short)bf16_rne(v[i] - bf16_f32(h));
        }
    }

    f32x4 acc[12];
    #pragma unroll
    for (int j = 0; j < 12; ++j) acc[j] = (f32x4){0.f, 0.f, 0.f, 0.f};

    #pragma unroll
    for (int hf = 0; hf < 2; ++hf) {
        if (hf) __syncthreads();         // protect LDS before overwrite
        // ---- stage 96 cols of W (hi+lo) into LDS, XOR-swizzled ----
        for (int gi = threadIdx.x; gi < 96 * 2 * GW; gi += 512) {
            const int ch = gi / (2 * GW);
            const int r  = gi - ch * 2 * GW;
            const int s  = r / GW;
            const int g  = r - s * GW;
            const u16* sp = (s == 0 ? wth : wtl)
                          + (size_t)(hf * 96 + ch) * K + g * 8;
            const short8 vv = *reinterpret_cast<const short8*>(sp);
            *reinterpret_cast<short8*>(
                &wlds[((ch * 2 + s) * GW + (g ^ (ch & GMW))) * 8]) = vv;
        }
        __syncthreads();

        #pragma unroll
        for (int j16h = 0; j16h < 6; ++j16h) {
            const int ch = j16h * 16 + rl;
            const u16* bbase = &wlds[(ch * 2) * GW * 8];
            #pragma unroll
            for (int kc = 0; kc < KC; ++kc) {
                const int gp = (kc * 4 + kb) ^ (ch & GMW);
                const short8 Bh =
                    *reinterpret_cast<const short8*>(bbase + gp * 8);
                const short8 Bl =
                    *reinterpret_cast<const short8*>(bbase + (GW + gp) * 8);
                f32x4 a = acc[hf * 6 + j16h];
                a = __builtin_amdgcn_mfma_f32_16x16x32_bf16(Ah[kc], Bh, a, 0, 0, 0);
                a = __builtin_amdgcn_mfma_f32_16x16x32_bf16(Ah[kc], Bl, a, 0, 0, 0);
                a = __builtin_amdgcn_mfma_f32_16x16x32_bf16(Al[kc], Bh, a, 0, 0, 0);
                acc[hf * 6 + j16h] = a;
            }
        }
    }

    // ---- epilogue: D[(kb*4+r)][rl] ----
    const int rowbase = n0 + w * 16 + kb * 4;
    #pragma unroll
    for (int j16 = 0; j16 < 4; ++j16) {          // cols 0..63 -> self + bias
        const float bj = bias[j16 * 16 + rl];
        #pragma unroll
        for (int r = 0; r < 4; ++r) {
            const int rr = rowbase + r;
            if (rr < nNodes)
                self[(size_t)rr * 64 + j16 * 16 + rl] = acc[j16][r] + bj;
        }
    }
    #pragma unroll
    for (int j16 = 4; j16 < 8; ++j16) {          // (basis0, basis1) pairs
        #pragma unroll
        for (int r = 0; r < 4; ++r) {
            const int rr = rowbase + r;
            if (rr < nNodes)
                hb2[(size_t)rr * 64 + (j16 - 4) * 16 + rl] =
                    make_float2(acc[j16][r], acc[j16 + 4][r]);
        }
    }
}

// ---------------- bucket build: fully parallel, no global atomics ----------
// block c owns edges [c*chunk, min(E,(c+1)*chunk))
__global__ __launch_bounds__(256) void bkt_count(
    const int* __restrict__ dst, int* __restrict__ cnt, int nE, int nB)
{
    __shared__ int lh[1024];
    const int t = threadIdx.x;
    for (int b = t; b < 1024; b += 256) lh[b] = 0;
    __syncthreads();
    const int chunk = (nE + NCHUNK - 1) / NCHUNK;
    const int e0 = blockIdx.x * chunk;
    const int e1 = min(nE, e0 + chunk);
    for (int e = e0 + t; e < e1; e += 256)
        atomicAdd(&lh[dst[e] >> 7], 1);
    __syncthreads();
    for (int b = t; b < nB; b += 256)
        cnt[blockIdx.x * nB + b] = lh[b];       // plain store
}

// one block per bucket: exclusive scan of its NCHUNK chunk-counts (in place)
__global__ __launch_bounds__(NCHUNK) void bkt_chunkscan(
    int* __restrict__ cnt, int* __restrict__ tot, int nB)
{
    __shared__ int sm[NCHUNK];
    const int b = blockIdx.x, t = threadIdx.x;
    const int v = cnt[t * nB + b];
    sm[t] = v;
    __syncthreads();
    for (int off = 1; off < NCHUNK; off <<= 1) {  // Hillis-Steele inclusive
        const int u = (t >= off) ? sm[t - off] : 0;
        __syncthreads();
        sm[t] += u;
        __syncthreads();
    }
    cnt[t * nB + b] = sm[t] - v;                  // exclusive
    if (t == NCHUNK - 1) tot[b] = sm[t];
}

// single small block: exclusive scan of bucket totals -> boff
__global__ __launch_bounds__(1024) void bkt_boff(
    const int* __restrict__ tot, int* __restrict__ boff, int nB, int nE)
{
    __shared__ int sm[1024];
    const int t = threadIdx.x;
    const int v = (t < nB) ? tot[t] : 0;
    sm[t] = v; __syncthreads();
    for (int off = 1; off < 1024; off <<= 1) {
        const int u = (t >= off) ? sm[t - off] : 0;
        __syncthreads();
        sm[t] += u;
        __syncthreads();
    }
    if (t < nB) boff[t] = sm[t] - v;              // exclusive
    if (t == 0) boff[nB] = nE;
}

// rec = dl(7)<<23 | src(17)<<6 | et(6); single pass, LDS cursors
__global__ __launch_bounds__(256) void bkt_scatter(
    const int* __restrict__ src, const int* __restrict__ dst,
    const int* __restrict__ et, const int* __restrict__ cnt,
    const int* __restrict__ boff, unsigned* __restrict__ rec,
    int nE, int nB)
{
    __shared__ int lcur[1024];
    const int t = threadIdx.x;
    const int c = blockIdx.x;
    for (int b = t; b < nB; b += 256)
        lcur[b] = boff[b] + cnt[c * nB + b];
    __syncthreads();
    const int chunk = (nE + NCHUNK - 1) / NCHUNK;
    const int e0 = c * chunk;
    const int e1 = min(nE, e0 + chunk);
    for (int e = e0 + t; e < e1; e += 256) {
        const int d = dst[e];
        const int p = atomicAdd(&lcur[d >> 7], 1);
        rec[p] = ((unsigned)(d & 127) << 23)
               | ((unsigned)src[e] << 6)
               | (unsigned)et[e];
    }
}

// ---------------- per-bucket counting sort by node; emits rowptr -----------
__global__ __launch_bounds__(256) void bkt_sort(
    const unsigned* __restrict__ rec, unsigned* __restrict__ rec2,
    const int* __restrict__ boff, int* __restrict__ rowptr,
    int nNodes)
{
    __shared__ int cnt[128];
    __shared__ int pos[128];
    const int b = blockIdx.x;
    const int t = threadIdx.x;
    const int beg = boff[b], end = boff[b + 1];
    if (t < 128) cnt[t] = 0;
    __syncthreads();
    for (int i = beg + t; i < end; i += 256)
        atomicAdd(&cnt[rec[i] >> 23], 1);
    __syncthreads();
    if (t < 128) pos[t] = cnt[t];
    __syncthreads();
    for (int off = 1; off < 128; off <<= 1) {     // Hillis-Steele inclusive
        int u = 0;
        if (t < 128 && t >= off) u = pos[t - off];
        __syncthreads();
        if (t < 128) pos[t] += u;
        __syncthreads();
    }
    if (t < 128) {
        const int ex = beg + pos[t] - cnt[t];     // exclusive + bucket base
        pos[t] = ex;
        const int n = (b << 7) + t;
        if (n < nNodes) rowptr[n] = ex;
    }
    __syncthreads();
    for (int i = beg + t; i < end; i += 256) {
        const unsigned r = rec[i];
        const int p = atomicAdd(&pos[r >> 23], 1);
        rec2[p] = r;                               // bucket-window write
    }
}

// ---------------- edge aggregation: one wave per node ----------------------
// Half-wave float4 gathers; fixed 8-pair batches with ALL loads issued before
// consumption (indices clamped to last edge, coeffs zeroed past cnt).
template<int ACT>   // 0 = tanh, 1 = relu
__global__ __launch_bounds__(256) void rgcn_agg(
    const float4* __restrict__ hb4,     // [N][32] float4 (=[N][64] float2)
    const float* __restrict__ comp,     // [R][2]
    const int* __restrict__ rowptr,     // [N], node-sorted rec2 offsets
    const unsigned* __restrict__ rec2,  // [E] node-grouped
    float* __restrict__ io,             // in: self+bias, out: act(self+agg)
    int nNodes, int nEdges)
{
    const int lane = threadIdx.x & 63;
    const int hl   = lane >> 5;         // 0: even edge of pair, 1: odd
    const int q    = lane & 31;         // float4 index (cols 2q, 2q+1)
    const int w  = (blockIdx.x * 256 + threadIdx.x) >> 6;
    const int nW = (gridDim.x * 256) >> 6;
    const float2* __restrict__ comp2 = reinterpret_cast<const float2*>(comp);
    for (int n = w; n < nNodes; n += nW) {
        const int beg = rowptr[n];
        const int end = (n == nNodes - 1) ? nEdges : rowptr[n + 1];
        const float2 self =
            *reinterpret_cast<const float2*>(io + (size_t)n * 64 + 2 * q);
        float accA = 0.f, accB = 0.f;
        for (int base = beg; base < end; base += 64) {
            const int cnt = min(64, end - base);
            const unsigned r = (lane < cnt) ? rec2[base + lane] : 0u;
            for (int i = 0; i < cnt; i += 16) {   // 8 pairs; 8 loads in flight
                unsigned rr[8]; bool ok[8];
                #pragma unroll
                for (int k = 0; k < 8; ++k) {
                    const int idx = i + 2 * k + hl;
                    ok[k] = idx < cnt;
                    rr[k] = __shfl(r, min(idx, cnt - 1));
                }
                float4 v[8];
                #pragma unroll
                for (int k = 0; k < 8; ++k)       // independent, back-to-back
                    v[k] = hb4[(size_t)((rr[k] >> 6) & 0x1FFFFu) * 32 + q];
                #pragma unroll
                for (int k = 0; k < 8; ++k) {
                    float2 c = comp2[rr[k] & 63u];
                    if (!ok[k]) { c.x = 0.f; c.y = 0.f; }
                    accA = fmaf(c.x, v[k].x, accA);
                    accA = fmaf(c.y, v[k].y, accA);
                    accB = fmaf(c.x, v[k].z, accB);
                    accB = fmaf(c.y, v[k].w, accB);
                }
            }
        }
        accA += __shfl_xor(accA, 32);             // combine halves
        accB += __shfl_xor(accB, 32);
        if (hl == 0) {
            float oA = self.x + accA, oB = self.y + accB;
            if (ACT == 0) { oA = tanhf(oA); oB = tanhf(oB); }
            else          { oA = fmaxf(oA, 0.f); oB = fmaxf(oB, 0.f); }
            *reinterpret_cast<float2*>(io + (size_t)n * 64 + 2 * q) =
                make_float2(oA, oB);
        }
    }
}

// ---------------------------------------------------------------------------
extern "C" void kernel_launch(void* const* d_in, const int* in_sizes, int n_in,
                              void* d_out, int out_size, void* d_ws, size_t ws_size,
                              hipStream_t stream)
{
    const float* node_emb = (const float*)d_in[0];   // [N][128]
    const float* basis1   = (const float*)d_in[1];   // [2][128][64]
    const float* comp1    = (const float*)d_in[2];   // [R][2]
    const float* loop_w1  = (const float*)d_in[3];   // [128][64]
    const float* bias1    = (const float*)d_in[4];   // [64]
    const float* basis2   = (const float*)d_in[5];   // [2][64][64]
    const float* comp2    = (const float*)d_in[6];   // [R][2]
    const float* loop_w2  = (const float*)d_in[7];   // [64][64]
    const float* bias2    = (const float*)d_in[8];   // [64]
    const int*   src      = (const int*)d_in[9];     // [E]
    const int*   dst      = (const int*)d_in[10];    // [E]
    const int*   et       = (const int*)d_in[11];    // [E]

    const int N = in_sizes[0] / 128;
    const int E = in_sizes[9];
    const int nB = (N + 127) / 128;                  // dst buckets (<=1024)

    float* out = (float*)d_out;                      // [N][64]

    // workspace layout
    float*    hb     = (float*)d_ws;                 // N*128 f (float4 [N][32])
    float*    h      = hb + (size_t)N * 128;         // N*64 f
    unsigned* rec    = (unsigned*)(h + (size_t)N * 64); // E u32 (bucket-grouped)
    unsigned* rec2   = rec + E;                      // E u32 (node-grouped)
    int*      cnt    = (int*)(rec2 + E);             // NCHUNK*nB
    int*      tot    = cnt + NCHUNK * nB;            // nB
    int*      boff   = tot + nB;                     // nB+1
    int*      rowptr = boff + nB + 1;                // N
    u16*      wt1h   = (u16*)(rowptr + N);           // 192*128
    u16*      wt1l   = wt1h + 192 * 128;
    u16*      wt2h   = wt1l + 192 * 128;             // 192*64
    u16*      wt2l   = wt2h + 192 * 64;

    const int nBlkDense = (N + 127) / 128;
    const int nBlkAgg   = (N + 3) / 4;               // 1 wave per node

    // ---- W pre-convert (bf16 hi/lo, transposed) ----
    wconv<<<96, 256, 0, stream>>>(loop_w1, basis1, loop_w2, basis2,
                                  wt1h, wt1l, wt2h, wt2l);

    // ---- per-node CSR: count -> chunkscan -> boff -> scatter -> sort ----
    bkt_count    <<<NCHUNK, 256, 0, stream>>>(dst, cnt, E, nB);
    bkt_chunkscan<<<nB, NCHUNK, 0, stream>>>(cnt, tot, nB);
    bkt_boff     <<<1,    1024, 0, stream>>>(tot, boff, nB, E);
    bkt_scatter  <<<NCHUNK, 256, 0, stream>>>(src, dst, et, cnt, boff, rec, E, nB);
    bkt_sort     <<<nB,     256, 0, stream>>>(rec, rec2, boff, rowptr, N);

    // ---- layer 1 ----
    rgcn_dense_mfma<128><<<nBlkDense, 512, 0, stream>>>(
        node_emb, wt1h, wt1l, bias1, h, (float2*)hb, N);
    rgcn_agg<0><<<nBlkAgg, 256, 0, stream>>>(
        (const float4*)hb, comp1, rowptr, rec2, h, N, E);

    // ---- layer 2 ----
    rgcn_dense_mfma<64><<<nBlkDense, 512, 0, stream>>>(
        h, wt2h, wt2l, bias2, out, (float2*)hb, N);
    rgcn_agg<1><<<nBlkAgg, 256, 0, stream>>>(
        (const float4*)hb, comp2, rowptr, rec2, out, N, E);
}

// Round 13
// 207.102 us; speedup vs baseline: 1.3934x; 1.3207x over previous
//
#include <hip/hip_runtime.h>
#include <math.h>

// ---------------------------------------------------------------------------
// R-GCN (basis decomposition, B=2), 2 layers.
//   C[n, 0:192] = x[n,:] @ [loop_w | basis0 | basis1]   (dense, MFMA bf16x3)
//   self = C[:,0:64]+bias ;  hbb[n][j] = pack(bf16 C[n,64+j], bf16 C[n,128+j])
//   out[n] = act(self[n] + sum_{e: dst=n} c0*b0[src][j] + c1*b1[src][j])
//
// Dense via matrix cores with fp32 emulation: x = xh + xl, w = wh + wl
// (bf16 hi/lo, RNE); C = xh*wh + xh*wl + xl*wh  (xl*wl ~ 2^-18, dropped).
//
// hb stored as PACKED BF16 PAIRS (u32/col): halves gather traffic per edge
// (512B -> 256B) -- r12 lesson: agg plateaued at FETCH 250MB from 8-XCD L2
// replication of the 51MB fp32 table; bytes/edge is the only lever.
//
// CSR build fully parallel (r9/r12): count -> chunkscan -> boff -> scatter
// -> per-bucket counting sort (rec2 + rowptr). No hot-line global atomics.
// Aggregation: one wave per node (64 lanes = 64 cols), 8-deep gather batches.
// ---------------------------------------------------------------------------

typedef short          short8 __attribute__((ext_vector_type(8)));
typedef float          f32x4  __attribute__((ext_vector_type(4)));
typedef unsigned short u16;

#define NCHUNK 256       // chunk blocks for count/scatter

static __device__ __forceinline__ u16 bf16_rne(float x) {
    unsigned u = __float_as_uint(x);
    return (u16)((u + 0x7fffu + ((u >> 16) & 1u)) >> 16);
}
static __device__ __forceinline__ float bf16_f32(u16 h) {
    return __uint_as_float(((unsigned)h) << 16);
}

// ---------------- W pre-convert: Wt[192][K] bf16 hi/lo (transposed) --------
__global__ __launch_bounds__(256) void wconv(
    const float* __restrict__ loopw1, const float* __restrict__ basis1,
    const float* __restrict__ loopw2, const float* __restrict__ basis2,
    u16* __restrict__ wt1h, u16* __restrict__ wt1l,
    u16* __restrict__ wt2h, u16* __restrict__ wt2l)
{
    const int tid = blockIdx.x * 256 + threadIdx.x;
    if (tid < 192 * 128) {                       // layer 1, K=128
        const int j = tid >> 7, k = tid & 127;
        const float w = (j < 64)
            ? loopw1[k * 64 + j]
            : basis1[(size_t)((j - 64) >> 6) * (128 * 64) + k * 64 + ((j - 64) & 63)];
        const u16 h = bf16_rne(w);
        wt1h[tid] = h;
        wt1l[tid] = bf16_rne(w - bf16_f32(h));
    }
    if (tid < 192 * 64) {                        // layer 2, K=64
        const int j = tid >> 6, k = tid & 63;
        const float w = (j < 64)
            ? loopw2[k * 64 + j]
            : basis2[(size_t)((j - 64) >> 6) * (64 * 64) + k * 64 + ((j - 64) & 63)];
        const u16 h = bf16_rne(w);
        wt2h[tid] = h;
        wt2l[tid] = bf16_rne(w - bf16_f32(h));
    }
}

// ---------------- dense: 128 nodes/block, 8 waves, W in LDS ----------------
template<int K>
__global__ __launch_bounds__(512, 2) void rgcn_dense_mfma(
    const float* __restrict__ x,     // [N][K] f32
    const u16* __restrict__ wth,     // [192][K] bf16 hi (transposed)
    const u16* __restrict__ wtl,     // [192][K] bf16 lo
    const float* __restrict__ bias,  // [64]
    float* __restrict__ self,        // [N][64]  = x@loopw + bias
    unsigned* __restrict__ hbb,      // [N][64]  = pack(bf16 b0, bf16 b1)
    int nNodes)
{
    constexpr int KC  = K / 32;          // mfma K-steps
    constexpr int GW  = K / 8;           // 16B granules per (col,split)
    constexpr int GMW = GW - 1;          // granule XOR mask
    __shared__ u16 wlds[96 * 2 * K];     // one 96-col half of W (hi+lo)

    const int n0   = blockIdx.x * 128;
    const int lane = threadIdx.x & 63;
    const int w    = threadIdx.x >> 6;   // 0..7
    const int rl   = lane & 15;          // A row / B col / D col
    const int kb   = lane >> 4;          // k-block

    // ---- A fragments: global -> reg, convert to bf16 hi/lo ----
    const int row = n0 + w * 16 + rl;
    short8 Ah[KC], Al[KC];
    #pragma unroll
    for (int kc = 0; kc < KC; ++kc) {
        float v[8];
        if (row < nNodes) {
            const float* xp = x + (size_t)row * K + kc * 32 + kb * 8;
            const float4 a = *reinterpret_cast<const float4*>(xp);
            const float4 b = *reinterpret_cast<const float4*>(xp + 4);
            v[0] = a.x; v[1] = a.y; v[2] = a.z; v[3] = a.w;
            v[4] = b.x; v[5] = b.y; v[6] = b.z; v[7] = b.w;
        } else {
            #pragma unroll
            for (int i = 0; i < 8; ++i) v[i] = 0.f;
        }
        #pragma unroll
        for (int i = 0; i < 8; ++i) {
            const u16 h = bf16_rne(v[i]);
            Ah[kc][i] = (short)h;
            Al[kc][i] = (short)bf16_rne(v[i] - bf16_f32(h));
        }
    }

    f32x4 acc[12];
    #pragma unroll
    for (int j = 0; j < 12; ++j) acc[j] = (f32x4){0.f, 0.f, 0.f, 0.f};

    #pragma unroll
    for (int hf = 0; hf < 2; ++hf) {
        if (hf) __syncthreads();         // protect LDS before overwrite
        // ---- stage 96 cols of W (hi+lo) into LDS, XOR-swizzled ----
        for (int gi = threadIdx.x; gi < 96 * 2 * GW; gi += 512) {
            const int ch = gi / (2 * GW);
            const int r  = gi - ch * 2 * GW;
            const int s  = r / GW;
            const int g  = r - s * GW;
            const u16* sp = (s == 0 ? wth : wtl)
                          + (size_t)(hf * 96 + ch) * K + g * 8;
            const short8 vv = *reinterpret_cast<const short8*>(sp);
            *reinterpret_cast<short8*>(
                &wlds[((ch * 2 + s) * GW + (g ^ (ch & GMW))) * 8]) = vv;
        }
        __syncthreads();

        #pragma unroll
        for (int j16h = 0; j16h < 6; ++j16h) {
            const int ch = j16h * 16 + rl;
            const u16* bbase = &wlds[(ch * 2) * GW * 8];
            #pragma unroll
            for (int kc = 0; kc < KC; ++kc) {
                const int gp = (kc * 4 + kb) ^ (ch & GMW);
                const short8 Bh =
                    *reinterpret_cast<const short8*>(bbase + gp * 8);
                const short8 Bl =
                    *reinterpret_cast<const short8*>(bbase + (GW + gp) * 8);
                f32x4 a = acc[hf * 6 + j16h];
                a = __builtin_amdgcn_mfma_f32_16x16x32_bf16(Ah[kc], Bh, a, 0, 0, 0);
                a = __builtin_amdgcn_mfma_f32_16x16x32_bf16(Ah[kc], Bl, a, 0, 0, 0);
                a = __builtin_amdgcn_mfma_f32_16x16x32_bf16(Al[kc], Bh, a, 0, 0, 0);
                acc[hf * 6 + j16h] = a;
            }
        }
    }

    // ---- epilogue: D[(kb*4+r)][rl] ----
    const int rowbase = n0 + w * 16 + kb * 4;
    #pragma unroll
    for (int j16 = 0; j16 < 4; ++j16) {          // cols 0..63 -> self + bias
        const float bj = bias[j16 * 16 + rl];
        #pragma unroll
        for (int r = 0; r < 4; ++r) {
            const int rr = rowbase + r;
            if (rr < nNodes)
                self[(size_t)rr * 64 + j16 * 16 + rl] = acc[j16][r] + bj;
        }
    }
    #pragma unroll
    for (int j16 = 4; j16 < 8; ++j16) {          // pack (b0,b1) -> u32
        #pragma unroll
        for (int r = 0; r < 4; ++r) {
            const int rr = rowbase + r;
            if (rr < nNodes)
                hbb[(size_t)rr * 64 + (j16 - 4) * 16 + rl] =
                    (unsigned)bf16_rne(acc[j16][r])
                  | ((unsigned)bf16_rne(acc[j16 + 4][r]) << 16);
        }
    }
}

// ---------------- bucket build: fully parallel, no global atomics ----------
// block c owns edges [c*chunk, min(E,(c+1)*chunk))
__global__ __launch_bounds__(256) void bkt_count(
    const int* __restrict__ dst, int* __restrict__ cnt, int nE, int nB)
{
    __shared__ int lh[1024];
    const int t = threadIdx.x;
    for (int b = t; b < 1024; b += 256) lh[b] = 0;
    __syncthreads();
    const int chunk = (nE + NCHUNK - 1) / NCHUNK;
    const int e0 = blockIdx.x * chunk;
    const int e1 = min(nE, e0 + chunk);
    for (int e = e0 + t; e < e1; e += 256)
        atomicAdd(&lh[dst[e] >> 7], 1);
    __syncthreads();
    for (int b = t; b < nB; b += 256)
        cnt[blockIdx.x * nB + b] = lh[b];       // plain store
}

// one block per bucket: exclusive scan of its NCHUNK chunk-counts (in place)
__global__ __launch_bounds__(NCHUNK) void bkt_chunkscan(
    int* __restrict__ cnt, int* __restrict__ tot, int nB)
{
    __shared__ int sm[NCHUNK];
    const int b = blockIdx.x, t = threadIdx.x;
    const int v = cnt[t * nB + b];
    sm[t] = v;
    __syncthreads();
    for (int off = 1; off < NCHUNK; off <<= 1) {  // Hillis-Steele inclusive
        const int u = (t >= off) ? sm[t - off] : 0;
        __syncthreads();
        sm[t] += u;
        __syncthreads();
    }
    cnt[t * nB + b] = sm[t] - v;                  // exclusive
    if (t == NCHUNK - 1) tot[b] = sm[t];
}

// single small block: exclusive scan of bucket totals -> boff
__global__ __launch_bounds__(1024) void bkt_boff(
    const int* __restrict__ tot, int* __restrict__ boff, int nB, int nE)
{
    __shared__ int sm[1024];
    const int t = threadIdx.x;
    const int v = (t < nB) ? tot[t] : 0;
    sm[t] = v; __syncthreads();
    for (int off = 1; off < 1024; off <<= 1) {
        const int u = (t >= off) ? sm[t - off] : 0;
        __syncthreads();
        sm[t] += u;
        __syncthreads();
    }
    if (t < nB) boff[t] = sm[t] - v;              // exclusive
    if (t == 0) boff[nB] = nE;
}

// rec = dl(7)<<23 | src(17)<<6 | et(6); single pass, LDS cursors
__global__ __launch_bounds__(256) void bkt_scatter(
    const int* __restrict__ src, const int* __restrict__ dst,
    const int* __restrict__ et, const int* __restrict__ cnt,
    const int* __restrict__ boff, unsigned* __restrict__ rec,
    int nE, int nB)
{
    __shared__ int lcur[1024];
    const int t = threadIdx.x;
    const int c = blockIdx.x;
    for (int b = t; b < nB; b += 256)
        lcur[b] = boff[b] + cnt[c * nB + b];
    __syncthreads();
    const int chunk = (nE + NCHUNK - 1) / NCHUNK;
    const int e0 = c * chunk;
    const int e1 = min(nE, e0 + chunk);
    for (int e = e0 + t; e < e1; e += 256) {
        const int d = dst[e];
        const int p = atomicAdd(&lcur[d >> 7], 1);
        rec[p] = ((unsigned)(d & 127) << 23)
               | ((unsigned)src[e] << 6)
               | (unsigned)et[e];
    }
}

// ---------------- per-bucket counting sort by node; emits rowptr -----------
__global__ __launch_bounds__(256) void bkt_sort(
    const unsigned* __restrict__ rec, unsigned* __restrict__ rec2,
    const int* __restrict__ boff, int* __restrict__ rowptr,
    int nNodes)
{
    __shared__ int cnt[128];
    __shared__ int pos[128];
    const int b = blockIdx.x;
    const int t = threadIdx.x;
    const int beg = boff[b], end = boff[b + 1];
    if (t < 128) cnt[t] = 0;
    __syncthreads();
    for (int i = beg + t; i < end; i += 256)
        atomicAdd(&cnt[rec[i] >> 23], 1);
    __syncthreads();
    if (t < 128) pos[t] = cnt[t];
    __syncthreads();
    for (int off = 1; off < 128; off <<= 1) {     // Hillis-Steele inclusive
        int u = 0;
        if (t < 128 && t >= off) u = pos[t - off];
        __syncthreads();
        if (t < 128) pos[t] += u;
        __syncthreads();
    }
    if (t < 128) {
        const int ex = beg + pos[t] - cnt[t];     // exclusive + bucket base
        pos[t] = ex;
        const int n = (b << 7) + t;
        if (n < nNodes) rowptr[n] = ex;
    }
    __syncthreads();
    for (int i = beg + t; i < end; i += 256) {
        const unsigned r = rec[i];
        const int p = atomicAdd(&pos[r >> 23], 1);
        rec2[p] = r;                               // bucket-window write
    }
}

// ---------------- edge aggregation: one wave per node, bf16-pair gathers ---
template<int ACT>   // 0 = tanh, 1 = relu
__global__ __launch_bounds__(256) void rgcn_agg(
    const unsigned* __restrict__ hbb,   // [N][64] u32 = (bf16 b0, bf16 b1)
    const float* __restrict__ comp,     // [R][2]
    const int* __restrict__ rowptr,     // [N], node-sorted rec2 offsets
    const unsigned* __restrict__ rec2,  // [E] node-grouped
    float* __restrict__ io,             // in: self+bias, out: act(self+agg)
    int nNodes, int nEdges)
{
    const int lane = threadIdx.x & 63;
    const int w  = (blockIdx.x * 256 + threadIdx.x) >> 6;
    const int nW = (gridDim.x * 256) >> 6;
    const float2* __restrict__ comp2 = reinterpret_cast<const float2*>(comp);
    for (int n = w; n < nNodes; n += nW) {
        const int beg = rowptr[n];
        const int end = (n == nNodes - 1) ? nEdges : rowptr[n + 1];
        const float self = io[(size_t)n * 64 + lane];   // issue early
        float acc0 = 0.f, acc1 = 0.f;
        for (int base = beg; base < end; base += 64) {
            const int cnt = min(64, end - base);
            const unsigned r = (lane < cnt) ? rec2[base + lane] : 0u;
            int i = 0;
            for (; i + 8 <= cnt; i += 8) {        // 8 gathers in flight
                unsigned rr[8], v[8];
                #pragma unroll
                for (int k = 0; k < 8; ++k) rr[k] = __shfl(r, i + k);
                #pragma unroll
                for (int k = 0; k < 8; ++k)
                    v[k] = hbb[(size_t)((rr[k] >> 6) & 0x1FFFFu) * 64 + lane];
                #pragma unroll
                for (int k = 0; k < 8; ++k) {
                    const float2 c = comp2[rr[k] & 63u];
                    acc0 = fmaf(c.x, __uint_as_float(v[k] << 16), acc0);
                    acc1 = fmaf(c.y, __uint_as_float(v[k] & 0xffff0000u), acc1);
                }
            }
            for (; i + 2 <= cnt; i += 2) {        // pair tail
                const unsigned rA = __shfl(r, i), rB = __shfl(r, i + 1);
                const unsigned vA =
                    hbb[(size_t)((rA >> 6) & 0x1FFFFu) * 64 + lane];
                const unsigned vB =
                    hbb[(size_t)((rB >> 6) & 0x1FFFFu) * 64 + lane];
                const float2 cA = comp2[rA & 63u], cB = comp2[rB & 63u];
                acc0 = fmaf(cA.x, __uint_as_float(vA << 16), acc0);
                acc1 = fmaf(cA.y, __uint_as_float(vA & 0xffff0000u), acc1);
                acc0 = fmaf(cB.x, __uint_as_float(vB << 16), acc0);
                acc1 = fmaf(cB.y, __uint_as_float(vB & 0xffff0000u), acc1);
            }
            if (i < cnt) {                        // single tail
                const unsigned rA = __shfl(r, i);
                const unsigned vA =
                    hbb[(size_t)((rA >> 6) & 0x1FFFFu) * 64 + lane];
                const float2 cA = comp2[rA & 63u];
                acc0 = fmaf(cA.x, __uint_as_float(vA << 16), acc0);
                acc1 = fmaf(cA.y, __uint_as_float(vA & 0xffff0000u), acc1);
            }
        }
        float o = self + acc0 + acc1;
        o = (ACT == 0) ? tanhf(o) : fmaxf(o, 0.f);
        io[(size_t)n * 64 + lane] = o;
    }
}

// ---------------------------------------------------------------------------
extern "C" void kernel_launch(void* const* d_in, const int* in_sizes, int n_in,
                              void* d_out, int out_size, void* d_ws, size_t ws_size,
                              hipStream_t stream)
{
    const float* node_emb = (const float*)d_in[0];   // [N][128]
    const float* basis1   = (const float*)d_in[1];   // [2][128][64]
    const float* comp1    = (const float*)d_in[2];   // [R][2]
    const float* loop_w1  = (const float*)d_in[3];   // [128][64]
    const float* bias1    = (const float*)d_in[4];   // [64]
    const float* basis2   = (const float*)d_in[5];   // [2][64][64]
    const float* comp2    = (const float*)d_in[6];   // [R][2]
    const float* loop_w2  = (const float*)d_in[7];   // [64][64]
    const float* bias2    = (const float*)d_in[8];   // [64]
    const int*   src      = (const int*)d_in[9];     // [E]
    const int*   dst      = (const int*)d_in[10];    // [E]
    const int*   et       = (const int*)d_in[11];    // [E]

    const int N = in_sizes[0] / 128;
    const int E = in_sizes[9];
    const int nB = (N + 127) / 128;                  // dst buckets (<=1024)

    float* out = (float*)d_out;                      // [N][64]

    // workspace layout
    unsigned* hbb    = (unsigned*)d_ws;              // N*64 u32 (packed pairs)
    float*    h      = (float*)(hbb + (size_t)N * 64); // N*64 f
    unsigned* rec    = (unsigned*)(h + (size_t)N * 64); // E u32 (bucket-grouped)
    unsigned* rec2   = rec + E;                      // E u32 (node-grouped)
    int*      cnt    = (int*)(rec2 + E);             // NCHUNK*nB
    int*      tot    = cnt + NCHUNK * nB;            // nB
    int*      boff   = tot + nB;                     // nB+1
    int*      rowptr = boff + nB + 1;                // N
    u16*      wt1h   = (u16*)(rowptr + N);           // 192*128
    u16*      wt1l   = wt1h + 192 * 128;
    u16*      wt2h   = wt1l + 192 * 128;             // 192*64
    u16*      wt2l   = wt2h + 192 * 64;

    const int nBlkDense = (N + 127) / 128;
    const int nBlkAgg   = (N + 3) / 4;               // 1 wave per node

    // ---- W pre-convert (bf16 hi/lo, transposed) ----
    wconv<<<96, 256, 0, stream>>>(loop_w1, basis1, loop_w2, basis2,
                                  wt1h, wt1l, wt2h, wt2l);

    // ---- per-node CSR: count -> chunkscan -> boff -> scatter -> sort ----
    bkt_count    <<<NCHUNK, 256, 0, stream>>>(dst, cnt, E, nB);
    bkt_chunkscan<<<nB, NCHUNK, 0, stream>>>(cnt, tot, nB);
    bkt_boff     <<<1,    1024, 0, stream>>>(tot, boff, nB, E);
    bkt_scatter  <<<NCHUNK, 256, 0, stream>>>(src, dst, et, cnt, boff, rec, E, nB);
    bkt_sort     <<<nB,     256, 0, stream>>>(rec, rec2, boff, rowptr, N);

    // ---- layer 1 ----
    rgcn_dense_mfma<128><<<nBlkDense, 512, 0, stream>>>(
        node_emb, wt1h, wt1l, bias1, h, hbb, N);
    rgcn_agg<0><<<nBlkAgg, 256, 0, stream>>>(
        hbb, comp1, rowptr, rec2, h, N, E);

    // ---- layer 2 ----
    rgcn_dense_mfma<64><<<nBlkDense, 512, 0, stream>>>(
        h, wt2h, wt2l, bias2, out, hbb, N);
    rgcn_agg<1><<<nBlkAgg, 256, 0, stream>>>(
        hbb, comp2, rowptr, rec2, out, N, E);
}

// Round 14
// 189.812 us; speedup vs baseline: 1.5203x; 1.0911x over previous
//
#include <hip/hip_runtime.h>
#include <math.h>

// ---------------------------------------------------------------------------
// R-GCN (basis decomposition, B=2), 2 layers.
//   C[n, 0:192] = x[n,:] @ [loop_w | basis0 | basis1]   (dense, MFMA bf16x3)
//   self = C[:,0:64]+bias ;  hbb[n][j] = pack(bf16 C[n,64+j], bf16 C[n,128+j])
//   out[n] = act(self[n] + sum_{e: dst=n} c0*b0[src][j] + c1*b1[src][j])
//
// Dense via matrix cores with fp32 emulation: x = xh + xl, w = wh + wl
// (bf16 hi/lo, RNE); C = xh*wh + xh*wl + xl*wh  (xl*wl ~ 2^-18, dropped).
//
// hb stored as PACKED BF16 PAIRS (u32/col): 256B/edge gather (r13: halved
// FETCH to 126MB, the algorithmic minimum x L2 replication).
//
// Aggregation (r14): src index and etype are WAVE-UNIFORM -> readfirstlane
// them to SGPRs: gathers become saddr-form global_load_dword (SALU base add,
// fixed voffset) and comp lookups become s_load via constant cache. Removes
// per-edge 64-bit vector address chains and per-edge VMEM table loads.
//
// CSR build fully parallel (r9/r12), wconv fused into count kernel (r14).
// ---------------------------------------------------------------------------

typedef short          short8 __attribute__((ext_vector_type(8)));
typedef float          f32x4  __attribute__((ext_vector_type(4)));
typedef unsigned short u16;

#define NCHUNK 256       // chunk blocks for count/scatter

static __device__ __forceinline__ u16 bf16_rne(float x) {
    unsigned u = __float_as_uint(x);
    return (u16)((u + 0x7fffu + ((u >> 16) & 1u)) >> 16);
}
static __device__ __forceinline__ float bf16_f32(u16 h) {
    return __uint_as_float(((unsigned)h) << 16);
}

// ---------------- prep: W pre-convert (96 blocks) + bucket count (256) -----
__device__ __forceinline__ void wconv_body(
    int tid,
    const float* __restrict__ loopw1, const float* __restrict__ basis1,
    const float* __restrict__ loopw2, const float* __restrict__ basis2,
    u16* __restrict__ wt1h, u16* __restrict__ wt1l,
    u16* __restrict__ wt2h, u16* __restrict__ wt2l)
{
    if (tid < 192 * 128) {                       // layer 1, K=128
        const int j = tid >> 7, k = tid & 127;
        const float w = (j < 64)
            ? loopw1[k * 64 + j]
            : basis1[(size_t)((j - 64) >> 6) * (128 * 64) + k * 64 + ((j - 64) & 63)];
        const u16 h = bf16_rne(w);
        wt1h[tid] = h;
        wt1l[tid] = bf16_rne(w - bf16_f32(h));
    }
    if (tid < 192 * 64) {                        // layer 2, K=64
        const int j = tid >> 6, k = tid & 63;
        const float w = (j < 64)
            ? loopw2[k * 64 + j]
            : basis2[(size_t)((j - 64) >> 6) * (64 * 64) + k * 64 + ((j - 64) & 63)];
        const u16 h = bf16_rne(w);
        wt2h[tid] = h;
        wt2l[tid] = bf16_rne(w - bf16_f32(h));
    }
}

__global__ __launch_bounds__(256) void prep_count(
    const int* __restrict__ dst, int* __restrict__ cnt, int nE, int nB,
    const float* __restrict__ loopw1, const float* __restrict__ basis1,
    const float* __restrict__ loopw2, const float* __restrict__ basis2,
    u16* __restrict__ wt1h, u16* __restrict__ wt1l,
    u16* __restrict__ wt2h, u16* __restrict__ wt2l)
{
    const int t = threadIdx.x;
    if (blockIdx.x >= NCHUNK) {                  // wconv part
        wconv_body((blockIdx.x - NCHUNK) * 256 + t,
                   loopw1, basis1, loopw2, basis2, wt1h, wt1l, wt2h, wt2l);
        return;
    }
    __shared__ int lh[1024];
    for (int b = t; b < 1024; b += 256) lh[b] = 0;
    __syncthreads();
    const int chunk = (nE + NCHUNK - 1) / NCHUNK;
    const int e0 = blockIdx.x * chunk;
    const int e1 = min(nE, e0 + chunk);
    for (int e = e0 + t; e < e1; e += 256)
        atomicAdd(&lh[dst[e] >> 7], 1);
    __syncthreads();
    for (int b = t; b < nB; b += 256)
        cnt[blockIdx.x * nB + b] = lh[b];        // plain store
}

// ---------------- dense: 128 nodes/block, 8 waves, W in LDS ----------------
template<int K>
__global__ __launch_bounds__(512, 2) void rgcn_dense_mfma(
    const float* __restrict__ x,     // [N][K] f32
    const u16* __restrict__ wth,     // [192][K] bf16 hi (transposed)
    const u16* __restrict__ wtl,     // [192][K] bf16 lo
    const float* __restrict__ bias,  // [64]
    float* __restrict__ self,        // [N][64]  = x@loopw + bias
    unsigned* __restrict__ hbb,      // [N][64]  = pack(bf16 b0, bf16 b1)
    int nNodes)
{
    constexpr int KC  = K / 32;          // mfma K-steps
    constexpr int GW  = K / 8;           // 16B granules per (col,split)
    constexpr int GMW = GW - 1;          // granule XOR mask
    __shared__ u16 wlds[96 * 2 * K];     // one 96-col half of W (hi+lo)

    const int n0   = blockIdx.x * 128;
    const int lane = threadIdx.x & 63;
    const int w    = threadIdx.x >> 6;   // 0..7
    const int rl   = lane & 15;          // A row / B col / D col
    const int kb   = lane >> 4;          // k-block

    // ---- A fragments: global -> reg, convert to bf16 hi/lo ----
    const int row = n0 + w * 16 + rl;
    short8 Ah[KC], Al[KC];
    #pragma unroll
    for (int kc = 0; kc < KC; ++kc) {
        float v[8];
        if (row < nNodes) {
            const float* xp = x + (size_t)row * K + kc * 32 + kb * 8;
            const float4 a = *reinterpret_cast<const float4*>(xp);
            const float4 b = *reinterpret_cast<const float4*>(xp + 4);
            v[0] = a.x; v[1] = a.y; v[2] = a.z; v[3] = a.w;
            v[4] = b.x; v[5] = b.y; v[6] = b.z; v[7] = b.w;
        } else {
            #pragma unroll
            for (int i = 0; i < 8; ++i) v[i] = 0.f;
        }
        #pragma unroll
        for (int i = 0; i < 8; ++i) {
            const u16 h = bf16_rne(v[i]);
            Ah[kc][i] = (short)h;
            Al[kc][i] = (short)bf16_rne(v[i] - bf16_f32(h));
        }
    }

    f32x4 acc[12];
    #pragma unroll
    for (int j = 0; j < 12; ++j) acc[j] = (f32x4){0.f, 0.f, 0.f, 0.f};

    #pragma unroll
    for (int hf = 0; hf < 2; ++hf) {
        if (hf) __syncthreads();         // protect LDS before overwrite
        // ---- stage 96 cols of W (hi+lo) into LDS, XOR-swizzled ----
        for (int gi = threadIdx.x; gi < 96 * 2 * GW; gi += 512) {
            const int ch = gi / (2 * GW);
            const int r  = gi - ch * 2 * GW;
            const int s  = r / GW;
            const int g  = r - s * GW;
            const u16* sp = (s == 0 ? wth : wtl)
                          + (size_t)(hf * 96 + ch) * K + g * 8;
            const short8 vv = *reinterpret_cast<const short8*>(sp);
            *reinterpret_cast<short8*>(
                &wlds[((ch * 2 + s) * GW + (g ^ (ch & GMW))) * 8]) = vv;
        }
        __syncthreads();

        #pragma unroll
        for (int j16h = 0; j16h < 6; ++j16h) {
            const int ch = j16h * 16 + rl;
            const u16* bbase = &wlds[(ch * 2) * GW * 8];
            #pragma unroll
            for (int kc = 0; kc < KC; ++kc) {
                const int gp = (kc * 4 + kb) ^ (ch & GMW);
                const short8 Bh =
                    *reinterpret_cast<const short8*>(bbase + gp * 8);
                const short8 Bl =
                    *reinterpret_cast<const short8*>(bbase + (GW + gp) * 8);
                f32x4 a = acc[hf * 6 + j16h];
                a = __builtin_amdgcn_mfma_f32_16x16x32_bf16(Ah[kc], Bh, a, 0, 0, 0);
                a = __builtin_amdgcn_mfma_f32_16x16x32_bf16(Ah[kc], Bl, a, 0, 0, 0);
                a = __builtin_amdgcn_mfma_f32_16x16x32_bf16(Al[kc], Bh, a, 0, 0, 0);
                acc[hf * 6 + j16h] = a;
            }
        }
    }

    // ---- epilogue: D[(kb*4+r)][rl] ----
    const int rowbase = n0 + w * 16 + kb * 4;
    #pragma unroll
    for (int j16 = 0; j16 < 4; ++j16) {          // cols 0..63 -> self + bias
        const float bj = bias[j16 * 16 + rl];
        #pragma unroll
        for (int r = 0; r < 4; ++r) {
            const int rr = rowbase + r;
            if (rr < nNodes)
                self[(size_t)rr * 64 + j16 * 16 + rl] = acc[j16][r] + bj;
        }
    }
    #pragma unroll
    for (int j16 = 4; j16 < 8; ++j16) {          // pack (b0,b1) -> u32
        #pragma unroll
        for (int r = 0; r < 4; ++r) {
            const int rr = rowbase + r;
            if (rr < nNodes)
                hbb[(size_t)rr * 64 + (j16 - 4) * 16 + rl] =
                    (unsigned)bf16_rne(acc[j16][r])
                  | ((unsigned)bf16_rne(acc[j16 + 4][r]) << 16);
        }
    }
}

// ---------------- bucket build (parallel scans) ----------------------------
// one block per bucket: exclusive scan of its NCHUNK chunk-counts (in place)
__global__ __launch_bounds__(NCHUNK) void bkt_chunkscan(
    int* __restrict__ cnt, int* __restrict__ tot, int nB)
{
    __shared__ int sm[NCHUNK];
    const int b = blockIdx.x, t = threadIdx.x;
    const int v = cnt[t * nB + b];
    sm[t] = v;
    __syncthreads();
    for (int off = 1; off < NCHUNK; off <<= 1) {  // Hillis-Steele inclusive
        const int u = (t >= off) ? sm[t - off] : 0;
        __syncthreads();
        sm[t] += u;
        __syncthreads();
    }
    cnt[t * nB + b] = sm[t] - v;                  // exclusive
    if (t == NCHUNK - 1) tot[b] = sm[t];
}

// single small block: exclusive scan of bucket totals -> boff
__global__ __launch_bounds__(1024) void bkt_boff(
    const int* __restrict__ tot, int* __restrict__ boff, int nB, int nE)
{
    __shared__ int sm[1024];
    const int t = threadIdx.x;
    const int v = (t < nB) ? tot[t] : 0;
    sm[t] = v; __syncthreads();
    for (int off = 1; off < 1024; off <<= 1) {
        const int u = (t >= off) ? sm[t - off] : 0;
        __syncthreads();
        sm[t] += u;
        __syncthreads();
    }
    if (t < nB) boff[t] = sm[t] - v;              // exclusive
    if (t == 0) boff[nB] = nE;
}

// rec = dl(7)<<23 | src(17)<<6 | et(6); single pass, LDS cursors
__global__ __launch_bounds__(256) void bkt_scatter(
    const int* __restrict__ src, const int* __restrict__ dst,
    const int* __restrict__ et, const int* __restrict__ cnt,
    const int* __restrict__ boff, unsigned* __restrict__ rec,
    int nE, int nB)
{
    __shared__ int lcur[1024];
    const int t = threadIdx.x;
    const int c = blockIdx.x;
    for (int b = t; b < nB; b += 256)
        lcur[b] = boff[b] + cnt[c * nB + b];
    __syncthreads();
    const int chunk = (nE + NCHUNK - 1) / NCHUNK;
    const int e0 = c * chunk;
    const int e1 = min(nE, e0 + chunk);
    for (int e = e0 + t; e < e1; e += 256) {
        const int d = dst[e];
        const int p = atomicAdd(&lcur[d >> 7], 1);
        rec[p] = ((unsigned)(d & 127) << 23)
               | ((unsigned)src[e] << 6)
               | (unsigned)et[e];
    }
}

// ---------------- per-bucket counting sort by node; emits rowptr -----------
__global__ __launch_bounds__(256) void bkt_sort(
    const unsigned* __restrict__ rec, unsigned* __restrict__ rec2,
    const int* __restrict__ boff, int* __restrict__ rowptr,
    int nNodes)
{
    __shared__ int cnt[128];
    __shared__ int pos[128];
    const int b = blockIdx.x;
    const int t = threadIdx.x;
    const int beg = boff[b], end = boff[b + 1];
    if (t < 128) cnt[t] = 0;
    __syncthreads();
    for (int i = beg + t; i < end; i += 256)
        atomicAdd(&cnt[rec[i] >> 23], 1);
    __syncthreads();
    if (t < 128) pos[t] = cnt[t];
    __syncthreads();
    for (int off = 1; off < 128; off <<= 1) {     // Hillis-Steele inclusive
        int u = 0;
        if (t < 128 && t >= off) u = pos[t - off];
        __syncthreads();
        if (t < 128) pos[t] += u;
        __syncthreads();
    }
    if (t < 128) {
        const int ex = beg + pos[t] - cnt[t];     // exclusive + bucket base
        pos[t] = ex;
        const int n = (b << 7) + t;
        if (n < nNodes) rowptr[n] = ex;
    }
    __syncthreads();
    for (int i = beg + t; i < end; i += 256) {
        const unsigned r = rec[i];
        const int p = atomicAdd(&pos[r >> 23], 1);
        rec2[p] = r;                               // bucket-window write
    }
}

// ---------------- edge aggregation: one wave per node ----------------------
// src/etype are wave-uniform -> readfirstlane to SGPR: gathers use saddr
// global_load (SALU base math), comp lookups use s_load (constant cache).
template<int ACT>   // 0 = tanh, 1 = relu
__global__ __launch_bounds__(256) void rgcn_agg(
    const unsigned* __restrict__ hbb,   // [N][64] u32 = (bf16 b0, bf16 b1)
    const float* __restrict__ comp,     // [R][2]
    const int* __restrict__ rowptr,     // [N], node-sorted rec2 offsets
    const unsigned* __restrict__ rec2,  // [E] node-grouped
    float* __restrict__ io,             // in: self+bias, out: act(self+agg)
    int nNodes, int nEdges)
{
    const int lane = threadIdx.x & 63;
    const int w  = (blockIdx.x * 256 + threadIdx.x) >> 6;
    const int nW = (gridDim.x * 256) >> 6;
    const float2* __restrict__ comp2 = reinterpret_cast<const float2*>(comp);
    for (int n = w; n < nNodes; n += nW) {
        const int beg = rowptr[n];
        const int end = (n == nNodes - 1) ? nEdges : rowptr[n + 1];
        const float self = io[(size_t)n * 64 + lane];   // issue early
        float acc0 = 0.f, acc1 = 0.f;
        for (int base = beg; base < end; base += 64) {
            const int cnt = min(64, end - base);
            const unsigned r = (lane < cnt) ? rec2[base + lane] : 0u;
            int i = 0;
            for (; i + 8 <= cnt; i += 8) {        // 8 saddr gathers in flight
                int ss[8], tt[8];
                #pragma unroll
                for (int k = 0; k < 8; ++k) {
                    const unsigned rk = __shfl(r, i + k);
                    ss[k] = __builtin_amdgcn_readfirstlane(
                                (int)((rk >> 6) & 0x1FFFFu));
                    tt[k] = __builtin_amdgcn_readfirstlane((int)(rk & 63u));
                }
                unsigned v[8];
                #pragma unroll
                for (int k = 0; k < 8; ++k)
                    v[k] = hbb[(size_t)ss[k] * 64 + lane];
                #pragma unroll
                for (int k = 0; k < 8; ++k) {
                    const float2 c = comp2[tt[k]];
                    acc0 = fmaf(c.x, __uint_as_float(v[k] << 16), acc0);
                    acc1 = fmaf(c.y, __uint_as_float(v[k] & 0xffff0000u), acc1);
                }
            }
            for (; i + 2 <= cnt; i += 2) {        // pair tail
                const unsigned rA = __shfl(r, i), rB = __shfl(r, i + 1);
                const int sA = __builtin_amdgcn_readfirstlane(
                                   (int)((rA >> 6) & 0x1FFFFu));
                const int sB = __builtin_amdgcn_readfirstlane(
                                   (int)((rB >> 6) & 0x1FFFFu));
                const int tA = __builtin_amdgcn_readfirstlane((int)(rA & 63u));
                const int tB = __builtin_amdgcn_readfirstlane((int)(rB & 63u));
                const unsigned vA = hbb[(size_t)sA * 64 + lane];
                const unsigned vB = hbb[(size_t)sB * 64 + lane];
                const float2 cA = comp2[tA], cB = comp2[tB];
                acc0 = fmaf(cA.x, __uint_as_float(vA << 16), acc0);
                acc1 = fmaf(cA.y, __uint_as_float(vA & 0xffff0000u), acc1);
                acc0 = fmaf(cB.x, __uint_as_float(vB << 16), acc0);
                acc1 = fmaf(cB.y, __uint_as_float(vB & 0xffff0000u), acc1);
            }
            if (i < cnt) {                        // single tail
                const unsigned rA = __shfl(r, i);
                const int sA = __builtin_amdgcn_readfirstlane(
                                   (int)((rA >> 6) & 0x1FFFFu));
                const int tA = __builtin_amdgcn_readfirstlane((int)(rA & 63u));
                const unsigned vA = hbb[(size_t)sA * 64 + lane];
                const float2 cA = comp2[tA];
                acc0 = fmaf(cA.x, __uint_as_float(vA << 16), acc0);
                acc1 = fmaf(cA.y, __uint_as_float(vA & 0xffff0000u), acc1);
            }
        }
        float o = self + acc0 + acc1;
        o = (ACT == 0) ? tanhf(o) : fmaxf(o, 0.f);
        io[(size_t)n * 64 + lane] = o;
    }
}

// ---------------------------------------------------------------------------
extern "C" void kernel_launch(void* const* d_in, const int* in_sizes, int n_in,
                              void* d_out, int out_size, void* d_ws, size_t ws_size,
                              hipStream_t stream)
{
    const float* node_emb = (const float*)d_in[0];   // [N][128]
    const float* basis1   = (const float*)d_in[1];   // [2][128][64]
    const float* comp1    = (const float*)d_in[2];   // [R][2]
    const float* loop_w1  = (const float*)d_in[3];   // [128][64]
    const float* bias1    = (const float*)d_in[4];   // [64]
    const float* basis2   = (const float*)d_in[5];   // [2][64][64]
    const float* comp2    = (const float*)d_in[6];   // [R][2]
    const float* loop_w2  = (const float*)d_in[7];   // [64][64]
    const float* bias2    = (const float*)d_in[8];   // [64]
    const int*   src      = (const int*)d_in[9];     // [E]
    const int*   dst      = (const int*)d_in[10];    // [E]
    const int*   et       = (const int*)d_in[11];    // [E]

    const int N = in_sizes[0] / 128;
    const int E = in_sizes[9];
    const int nB = (N + 127) / 128;                  // dst buckets (<=1024)

    float* out = (float*)d_out;                      // [N][64]

    // workspace layout
    unsigned* hbb    = (unsigned*)d_ws;              // N*64 u32 (packed pairs)
    float*    h      = (float*)(hbb + (size_t)N * 64); // N*64 f
    unsigned* rec    = (unsigned*)(h + (size_t)N * 64); // E u32 (bucket-grouped)
    unsigned* rec2   = rec + E;                      // E u32 (node-grouped)
    int*      cnt    = (int*)(rec2 + E);             // NCHUNK*nB
    int*      tot    = cnt + NCHUNK * nB;            // nB
    int*      boff   = tot + nB;                     // nB+1
    int*      rowptr = boff + nB + 1;                // N
    u16*      wt1h   = (u16*)(rowptr + N);           // 192*128
    u16*      wt1l   = wt1h + 192 * 128;
    u16*      wt2h   = wt1l + 192 * 128;             // 192*64
    u16*      wt2l   = wt2h + 192 * 64;

    const int nBlkDense = (N + 127) / 128;
    const int nBlkAgg   = (N + 3) / 4;               // 1 wave per node

    // ---- prep: wconv + bucket count (fused, independent halves) ----
    prep_count<<<NCHUNK + 96, 256, 0, stream>>>(
        dst, cnt, E, nB, loop_w1, basis1, loop_w2, basis2,
        wt1h, wt1l, wt2h, wt2l);

    // ---- per-node CSR: chunkscan -> boff -> scatter -> sort ----
    bkt_chunkscan<<<nB, NCHUNK, 0, stream>>>(cnt, tot, nB);
    bkt_boff     <<<1,    1024, 0, stream>>>(tot, boff, nB, E);
    bkt_scatter  <<<NCHUNK, 256, 0, stream>>>(src, dst, et, cnt, boff, rec, E, nB);
    bkt_sort     <<<nB,     256, 0, stream>>>(rec, rec2, boff, rowptr, N);

    // ---- layer 1 ----
    rgcn_dense_mfma<128><<<nBlkDense, 512, 0, stream>>>(
        node_emb, wt1h, wt1l, bias1, h, hbb, N);
    rgcn_agg<0><<<nBlkAgg, 256, 0, stream>>>(
        hbb, comp1, rowptr, rec2, h, N, E);

    // ---- layer 2 ----
    rgcn_dense_mfma<64><<<nBlkDense, 512, 0, stream>>>(
        h, wt2h, wt2l, bias2, out, hbb, N);
    rgcn_agg<1><<<nBlkAgg, 256, 0, stream>>>(
        hbb, comp2, rowptr, rec2, out, N, E);
}